// Round 11
// baseline (51896.771 us; speedup 1.0000x reference)
//
#include <hip/hip_runtime.h>
#include <math.h>

typedef unsigned short u16;

static constexpr int Bsz = 64;
static constexpr int Tt  = 512;
static constexpr int INF = 256;
static constexpr int Hf  = 512;
static constexpr int OUTF = 10;
static constexpr int NBLK = 256;   // 128 col-groups x 2 batch-halves
static constexpr int NTHR = 1024;  // 16 waves

__device__ __forceinline__ float sigmoidf_(float x) {
    return 1.0f / (1.0f + __expf(-x));
}
__device__ __forceinline__ float tanhf_(float x) {
    float e = __expf(-2.0f * fabsf(x));
    float r = (1.0f - e) / (1.0f + e);
    return copysignf(r, x);
}

// 4-byte agent-scope access (LLC-coherent, cache-served): the ONLY proven path.
__device__ __forceinline__ float ldc(const float* p) {
    return __hip_atomic_load(const_cast<float*>(p), __ATOMIC_RELAXED, __HIP_MEMORY_SCOPE_AGENT);
}
__device__ __forceinline__ void stc(float* p, float v) {
    __hip_atomic_store(p, v, __ATOMIC_RELAXED, __HIP_MEMORY_SCOPE_AGENT);
}
__device__ __forceinline__ unsigned ldcu(const unsigned* p) {
    return __hip_atomic_load(const_cast<unsigned*>(p), __ATOMIC_RELAXED, __HIP_MEMORY_SCOPE_AGENT);
}

// bf16 pair helpers: slab is [k][64] u16; a u32 load covers batches {2n, 2n+1}.
__device__ __forceinline__ float bsel(unsigned u, unsigned odd) {
    return __uint_as_float(odd ? (u & 0xffff0000u) : (u << 16));
}
// Writer: lane pair (bb even, bb odd) packs two bf16 into one scoped u32 store.
__device__ __forceinline__ void pairstore(u16* slab, int gi, float v) {
    unsigned x = __float_as_uint(v);
    unsigned bf = (x + 0x7fffu + ((x >> 16) & 1u)) >> 16;   // round-nearest-even
    unsigned other = (unsigned)__shfl_xor((int)bf, 1);
    if (!(gi & 1))
        __hip_atomic_store((unsigned*)slab + (gi >> 1), bf | (other << 16),
                           __ATOMIC_RELAXED, __HIP_MEMORY_SCOPE_AGENT);
}

// Per-half flag barrier (r3-proven).
__device__ __forceinline__ void gsync(unsigned* flags, int myflag, int pollbase, unsigned gen) {
    __syncthreads();
    const int tid = threadIdx.x;
    if (tid == 0)
        __hip_atomic_store(&flags[myflag], gen, __ATOMIC_RELAXED, __HIP_MEMORY_SCOPE_AGENT);
    if (tid < 128) {
        const unsigned* f = &flags[pollbase + tid];
        while (__hip_atomic_load(const_cast<unsigned*>(f), __ATOMIC_RELAXED, __HIP_MEMORY_SCOPE_AGENT) < gen)
            __builtin_amdgcn_s_sleep(2);
    }
    __syncthreads();
}

// x (B,T,IN) -> xT (T,IN,B)
__global__ __launch_bounds__(256) void transpose_x_k(const float* __restrict__ x,
                                                     float* __restrict__ xT) {
    __shared__ float tile[64][65];
    int t  = blockIdx.x;
    int k0 = blockIdx.y * 64;
    int tid = threadIdx.x;
#pragma unroll
    for (int i = 0; i < 16; ++i) {
        int idx = i * 256 + tid;
        int bb = idx >> 6, kk = idx & 63;
        tile[bb][kk] = x[(size_t)bb * Tt * INF + (size_t)t * INF + k0 + kk];
    }
    __syncthreads();
#pragma unroll
    for (int i = 0; i < 16; ++i) {
        int idx = i * 256 + tid;
        int kk = idx >> 6, bb = idx & 63;
        xT[(size_t)t * INF * 64 + (size_t)(k0 + kk) * 64 + bb] = tile[bb][kk];
    }
}

#define FMA2(a, w, v) { (a).x = fmaf((w).x, (v), (a).x); (a).y = fmaf((w).y, (v), (a).y); }
#define W2(base, idx) (((const float2*)(base))[(size_t)(idx) * 2 + cs])

// Persistent layer kernel (r3 structure). Block (cg,bh): cols [cg*4,+4),
// batches [bh*32,+32). fp32 own-state slabs + bf16 broadcast mirrors.
template<int LIN, bool WRITE_Y>
__global__ __launch_bounds__(NTHR, 4) void esn_persist_k(
    const float* __restrict__ xT, float* __restrict__ y,
    float* rA, float* rB, float* hA, float* hB,
    u16* r16A, u16* r16B, u16* h16A, u16* h16B,
    u16* rh16, u16* hg16,
    const float* __restrict__ Win, const float* __restrict__ Wres,
    const float* __restrict__ Wz, const float* __restrict__ bz,
    const float* __restrict__ Wr, const float* __restrict__ br,
    const float* __restrict__ Wc, const float* __restrict__ bc,
    const float* __restrict__ Wg, const float* __restrict__ bg,
    const float* __restrict__ Wp, const float* __restrict__ bp,
    unsigned* flags)
{
    constexpr int R4 = LIN + 512;
    constexpr int ROWS = 4 * R4 + LIN + 3 * 512;
    constexpr int CX = LIN / 16;

    extern __shared__ char smem[];
    float4* wRES = (float4*)smem;
    float4* wZ   = wRES + R4;
    float4* wR   = wZ + R4;
    float4* wC   = wR + R4;
    float4* wGx  = wC + R4;
    float4* wGh  = wGx + LIN;
    float4* wGr  = wGh + 512;
    float4* wP   = wGr + 512;
    float*  pb   = (float*)(smem + (size_t)ROWS * 16);
    float*  lz   = pb + 8192;
    float*  lgx  = lz + 128;
    float*  lp   = lgx + 128;
    float*  lgg  = lp + 128;
    float*  lhg  = lgg + 128;

    const int tid  = threadIdx.x;
    const int lane = tid & 63;
    const int wv   = tid >> 6;
    const int b    = lane & 31;
    const int cs   = lane >> 5;
    const int cg   = blockIdx.x & 127;
    const int bh   = blockIdx.x >> 7;
    const int c0   = cg * 4;
    const int boff = bh * 32;
    const int myflag = bh * 128 + cg;
    const int pollbase = bh * 128;
    const unsigned odd = b & 1;
    const int poff = (boff + (b & ~1)) >> 1;   // u32 index within a 32-u32 k-row

    // ---- stage 4 columns of every matrix into LDS
    for (int k = tid; k < LIN; k += NTHR) {
        wRES[k] = *(const float4*)&Win[(size_t)k * 512 + c0];
        wGx[k]  = *(const float4*)&Wg[(size_t)k * 512 + c0];
    }
    for (int k = tid; k < R4; k += NTHR) {
        wZ[k] = *(const float4*)&Wz[(size_t)k * 512 + c0];
        wR[k] = *(const float4*)&Wr[(size_t)k * 512 + c0];
        wC[k] = *(const float4*)&Wc[(size_t)k * 512 + c0];
    }
    for (int k = tid; k < 512; k += NTHR) {
        wRES[LIN + k] = *(const float4*)&Wres[(size_t)k * 512 + c0];
        wGh[k] = *(const float4*)&Wg[(size_t)(LIN + k) * 512 + c0];
        wGr[k] = *(const float4*)&Wg[(size_t)(LIN + 512 + k) * 512 + c0];
        wP[k]  = *(const float4*)&Wp[(size_t)k * 512 + c0];
    }
    __syncthreads();

    float* rc = rA; float* rn = rB; float* hc = hA; float* hn = hB;
    u16* r16c = r16A; u16* r16n = r16B; u16* h16c = h16A; u16* h16n = h16B;
    unsigned gen = 0;

    for (int t = 0; t < Tt; ++t) {
        const float* xt = xT + (size_t)t * LIN * 64;

        // ============ phase A: r_new, z, rh, gx ============
        {
            float2 aRES = {0, 0}, aZ = {0, 0}, aR = {0, 0}, aG = {0, 0};
            {
                const float* xb = xt + boff + b;
                int k0 = wv * CX;
#pragma unroll 8
                for (int k = k0; k < k0 + CX; ++k) {
                    float xv = xb[k * 64];
                    float2 w;
                    w = W2(wRES, k); FMA2(aRES, w, xv);
                    w = W2(wZ, k);   FMA2(aZ, w, xv);
                    w = W2(wR, k);   FMA2(aR, w, xv);
                    w = W2(wGx, k);  FMA2(aG, w, xv);
                }
            }
            {
                const unsigned* r16u = (const unsigned*)r16c;
                const unsigned* h16u = (const unsigned*)h16c;
                int k0 = wv * 32;
#pragma unroll 8
                for (int k = k0; k < k0 + 32; ++k) {
                    float rv = bsel(ldcu(r16u + k * 32 + poff), odd);
                    float hv = bsel(ldcu(h16u + k * 32 + poff), odd);
                    float2 w;
                    w = W2(wRES, LIN + k); FMA2(aRES, w, rv);
                    w = W2(wZ, LIN + k);   FMA2(aZ, w, hv);
                    w = W2(wR, LIN + k);   FMA2(aR, w, hv);
                }
            }
            float2* pb2 = (float2*)pb;
            pb2[(0 * 16 + wv) * 64 + lane] = aRES;
            pb2[(1 * 16 + wv) * 64 + lane] = aZ;
            pb2[(2 * 16 + wv) * 64 + lane] = aR;
            pb2[(3 * 16 + wv) * 64 + lane] = aG;
            __syncthreads();
            if (tid < 512) {
                int m = tid >> 7, rem = tid & 127, c = rem >> 5, bb = rem & 31;
                int pl = (bb + 32 * (c >> 1)) * 2 + (c & 1);
                float s = 0.f;
#pragma unroll
                for (int w = 0; w < 16; ++w) s += pb[(m * 16 + w) * 128 + pl];
                int cab = c0 + c;
                int gi = cab * 64 + boff + bb;
                if (m == 0) {
                    float ro = ldc(rc + gi);
                    float val = 0.7f * ro + 0.3f * tanhf_(s);
                    stc(rn + gi, val);
                    pairstore(r16n, gi, val);
                } else if (m == 1) {
                    lz[c * 32 + bb] = sigmoidf_(s + bz[cab]);
                } else if (m == 2) {
                    float hv = ldc(hc + gi);
                    pairstore(rh16, gi, sigmoidf_(s + br[cab]) * hv);
                } else {
                    lgx[c * 32 + bb] = s;
                }
            }
            gsync(flags, myflag, pollbase, ++gen);
        }

        // ============ phase B: h_gru, p, gg ============
        {
            float2 aC = {0, 0}, aP = {0, 0}, aGr = {0, 0};
            {
                const float* xb = xt + boff + b;
                int k0 = wv * CX;
#pragma unroll 8
                for (int k = k0; k < k0 + CX; ++k) {
                    float xv = xb[k * 64];
                    float2 w = W2(wC, k);
                    FMA2(aC, w, xv);
                }
            }
            {
                const unsigned* rn16u = (const unsigned*)r16n;
                const unsigned* rh16u = (const unsigned*)rh16;
                int k0 = wv * 32;
#pragma unroll 8
                for (int k = k0; k < k0 + 32; ++k) {
                    float rnv = bsel(ldcu(rn16u + k * 32 + poff), odd);
                    float rhv = bsel(ldcu(rh16u + k * 32 + poff), odd);
                    float2 w;
                    w = W2(wC, LIN + k); FMA2(aC, w, rhv);
                    w = W2(wP, k);       FMA2(aP, w, rnv);
                    w = W2(wGr, k);      FMA2(aGr, w, rnv);
                }
            }
            float2* pb2 = (float2*)pb;
            pb2[(0 * 16 + wv) * 64 + lane] = aC;
            pb2[(1 * 16 + wv) * 64 + lane] = aP;
            pb2[(2 * 16 + wv) * 64 + lane] = aGr;
            __syncthreads();
            if (tid < 384) {
                int m = tid >> 7, rem = tid & 127, c = rem >> 5, bb = rem & 31;
                int pl = (bb + 32 * (c >> 1)) * 2 + (c & 1);
                float s = 0.f;
#pragma unroll
                for (int w = 0; w < 16; ++w) s += pb[(m * 16 + w) * 128 + pl];
                int cab = c0 + c;
                int gi = cab * 64 + boff + bb;
                if (m == 0) {
                    float cand = tanhf_(s + bc[cab]);
                    float z = lz[c * 32 + bb];
                    float hv = ldc(hc + gi);
                    float hg = (1.f - z) * hv + z * cand;
                    pairstore(hg16, gi, hg);
                    lhg[c * 32 + bb] = hg;
                } else if (m == 1) {
                    lp[c * 32 + bb] = tanhf_(s + bp[cab]);
                } else {
                    lgg[c * 32 + bb] = s + lgx[c * 32 + bb];
                }
            }
            gsync(flags, myflag, pollbase, ++gen);
        }

        // ============ phase C: g, h_new ============
        {
            float2 aGh = {0, 0};
            {
                const unsigned* hg16u = (const unsigned*)hg16;
                int k0 = wv * 32;
#pragma unroll 8
                for (int k = k0; k < k0 + 32; ++k) {
                    float hgv = bsel(ldcu(hg16u + k * 32 + poff), odd);
                    float2 w = W2(wGh, k);
                    FMA2(aGh, w, hgv);
                }
            }
            ((float2*)pb)[(0 * 16 + wv) * 64 + lane] = aGh;
            __syncthreads();
            if (tid < 128) {
                int c = tid >> 5, bb = tid & 31;
                int pl = (bb + 32 * (c >> 1)) * 2 + (c & 1);
                float s = 0.f;
#pragma unroll
                for (int w = 0; w < 16; ++w) s += pb[w * 128 + pl];
                int cab = c0 + c;
                int gi = cab * 64 + boff + bb;
                float g = sigmoidf_(s + lgg[c * 32 + bb] + bg[cab]);
                float hgv = lhg[c * 32 + bb];
                float hnv = (1.f - g) * hgv + g * lp[c * 32 + bb];
                stc(hn + gi, hnv);
                pairstore(h16n, gi, hnv);
                if (WRITE_Y) y[(size_t)t * (Hf * 64) + gi] = hnv;   // normal store, next kernel reads
            }
            gsync(flags, myflag, pollbase, ++gen);
        }

        float* tp = rc; rc = rn; rn = tp;
        tp = hc; hc = hn; hn = tp;
        u16* tq = r16c; r16c = r16n; r16n = tq;
        tq = h16c; h16c = h16n; h16n = tq;
    }
}
#undef W2

// Head: hid = relu(last@Wo1 + bo1)
__global__ __launch_bounds__(256) void head1_k(const float* __restrict__ hlast,
                                               const float* __restrict__ Wo1,
                                               const float* __restrict__ bo1,
                                               float* __restrict__ hidT) {
    int tid = threadIdx.x;
    int b = tid & 63, jg = tid >> 6;
    int j0 = blockIdx.x * 16 + jg * 4;
    float acc[4] = {0.f, 0.f, 0.f, 0.f};
    const float* ap = hlast + b;
    const float* wp = Wo1 + j0;
#pragma unroll 4
    for (int k = 0; k < Hf; ++k) {
        float xv = ap[k * 64];
        const float4 w = *reinterpret_cast<const float4*>(wp + k * 512);
        acc[0] = fmaf(w.x, xv, acc[0]);
        acc[1] = fmaf(w.y, xv, acc[1]);
        acc[2] = fmaf(w.z, xv, acc[2]);
        acc[3] = fmaf(w.w, xv, acc[3]);
    }
#pragma unroll
    for (int jj = 0; jj < 4; ++jj) {
        int j = j0 + jj;
        hidT[j * 64 + b] = fmaxf(acc[jj] + bo1[j], 0.f);
    }
}

__global__ __launch_bounds__(640) void head2_k(const float* __restrict__ hidT,
                                               const float* __restrict__ Wo2,
                                               const float* __restrict__ bo2,
                                               float* __restrict__ out) {
    int tid = threadIdx.x;
    if (tid >= Bsz * OUTF) return;
    int b = tid / OUTF, o = tid % OUTF;
    float acc = 0.f;
    for (int k = 0; k < Hf; ++k)
        acc = fmaf(hidT[k * 64 + b], Wo2[k * OUTF + o], acc);
    out[tid] = acc + bo2[o];
}

struct LayerW {
    const float *Win, *Wres, *Wz, *bz, *Wr, *br, *Wc, *bc, *Wg, *bg, *Wp, *bp;
};

extern "C" void kernel_launch(void* const* d_in, const int* in_sizes, int n_in,
                              void* d_out, int out_size, void* d_ws, size_t ws_size,
                              hipStream_t stream) {
    const float* x = (const float*)d_in[0];
    LayerW L[2];
    int idx = 1;
    for (int li = 0; li < 2; ++li) {
        L[li].Win  = (const float*)d_in[idx++];
        L[li].Wres = (const float*)d_in[idx++];
        L[li].Wz   = (const float*)d_in[idx++];
        L[li].bz   = (const float*)d_in[idx++];
        L[li].Wr   = (const float*)d_in[idx++];
        L[li].br   = (const float*)d_in[idx++];
        L[li].Wc   = (const float*)d_in[idx++];
        L[li].bc   = (const float*)d_in[idx++];
        L[li].Wg   = (const float*)d_in[idx++];
        L[li].bg   = (const float*)d_in[idx++];
        L[li].Wp   = (const float*)d_in[idx++];
        L[li].bp   = (const float*)d_in[idx++];
    }
    const float* Wo1 = (const float*)d_in[idx++];
    const float* bo1 = (const float*)d_in[idx++];
    const float* Wo2 = (const float*)d_in[idx++];
    const float* bo2 = (const float*)d_in[idx++];

    char* ws = (char*)d_ws;
    size_t off = 0;
    auto walloc = [&](size_t bytes) -> void* {
        void* p = (void*)(ws + off);
        off += (bytes + 255) & ~(size_t)255;
        return p;
    };
    const size_t STATE = (size_t)Hf * 64 * sizeof(float); // 128 KiB
    const size_t STATE16 = (size_t)Hf * 64 * sizeof(u16); // 64 KiB
    float* xT0 = (float*)walloc((size_t)Tt * INF * 64 * sizeof(float)); // 33.5 MB
    float* y0  = (float*)walloc((size_t)Tt * Hf * 64 * sizeof(float));  // 67 MB
    float* rA  = (float*)walloc(STATE);
    float* rB  = (float*)walloc(STATE);
    float* hA  = (float*)walloc(STATE);
    float* hB  = (float*)walloc(STATE);
    u16* r16A = (u16*)walloc(STATE16);
    u16* r16B = (u16*)walloc(STATE16);
    u16* h16A = (u16*)walloc(STATE16);
    u16* h16B = (u16*)walloc(STATE16);
    u16* rh16 = (u16*)walloc(STATE16);
    u16* hg16 = (u16*)walloc(STATE16);
    float* hidT = (float*)walloc(STATE);
    unsigned* flags = (unsigned*)walloc(NBLK * sizeof(unsigned));
    (void)ws_size;

    constexpr unsigned SMEM0 = (5 * INF + 3584) * 16 + 32768 + 2560; // 113,152
    constexpr unsigned SMEM1 = (5 * Hf  + 3584) * 16 + 32768 + 2560; // 133,632
    hipFuncSetAttribute((const void*)esn_persist_k<INF, true>,
                        hipFuncAttributeMaxDynamicSharedMemorySize, SMEM0);
    hipFuncSetAttribute((const void*)esn_persist_k<Hf, false>,
                        hipFuncAttributeMaxDynamicSharedMemorySize, SMEM1);

    transpose_x_k<<<dim3(Tt, INF / 64), 256, 0, stream>>>(x, xT0);

    // ---- layer 0
    hipMemsetAsync(flags, 0, NBLK * sizeof(unsigned), stream);
    hipMemsetAsync(rA, 0, STATE, stream);
    hipMemsetAsync(hA, 0, STATE, stream);
    hipMemsetAsync(r16A, 0, STATE16, stream);
    hipMemsetAsync(h16A, 0, STATE16, stream);
    esn_persist_k<INF, true><<<NBLK, NTHR, SMEM0, stream>>>(
        xT0, y0, rA, rB, hA, hB, r16A, r16B, h16A, h16B, rh16, hg16,
        L[0].Win, L[0].Wres, L[0].Wz, L[0].bz, L[0].Wr, L[0].br,
        L[0].Wc, L[0].bc, L[0].Wg, L[0].bg, L[0].Wp, L[0].bp, flags);

    // ---- layer 1
    hipMemsetAsync(flags, 0, NBLK * sizeof(unsigned), stream);
    hipMemsetAsync(rA, 0, STATE, stream);
    hipMemsetAsync(hA, 0, STATE, stream);
    hipMemsetAsync(r16A, 0, STATE16, stream);
    hipMemsetAsync(h16A, 0, STATE16, stream);
    esn_persist_k<Hf, false><<<NBLK, NTHR, SMEM1, stream>>>(
        y0, nullptr, rA, rB, hA, hB, r16A, r16B, h16A, h16B, rh16, hg16,
        L[1].Win, L[1].Wres, L[1].Wz, L[1].bz, L[1].Wr, L[1].br,
        L[1].Wc, L[1].bc, L[1].Wg, L[1].bg, L[1].Wp, L[1].bp, flags);

    // 512 steps (even) -> final h is back in hA.
    head1_k<<<dim3(32, 1), 256, 0, stream>>>(hA, Wo1, bo1, hidT);
    head2_k<<<dim3(1, 1), 640, 0, stream>>>(hidT, Wo2, bo2, (float*)d_out);
}